// Round 5
// baseline (100.206 us; speedup 1.0000x reference)
//
#include <hip/hip_runtime.h>

#define NQ    12
#define BATCH 8192

// ---------------------------------------------------------------------------
// One wave (64 lanes) simulates one batch element's 4096-dim real state:
// d = (lane << 6) | reg. Imag part is identically zero (RY real, perms real).
//
// Ring permutation (12 CNOTs) is GF(2)-linear; reg part rho and lane part sig
// (x -> x ^ ((x&31)<<1)) are deferred via compile-time renaming; CNOT(5,6)
// and CNOT(11,0) are executed explicitly with renamed indices/masks.
//
// RY gates use tan-form: RY(th) = c*[[1,-t],[t,1]], t=tan(th/2). The scalar
// c commutes with everything; G = prod(c) over all 48 theta gates is folded
// into the epilogue as G^2 (outputs are quadratic in the state).
//
// This round: force the state into ARCH VGPRs (waves_per_eu(2) budget +
// asm "+v" pinning) to kill v_accvgpr_read/write shuttling around DPP/FMA.
// ---------------------------------------------------------------------------

constexpr int sig6(int x)            { return (x ^ (x << 1)) & 63; }
constexpr int sigpow6(int x, int t)  { return t == 0 ? x : sigpow6(sig6(x), t - 1); }
// bit_j(sig^-t(p)) = parity(p & rowmask6(j,t));  sig^8 = I
constexpr int rowmask6(int j, int t) {
    int tt = (8 - (t % 8)) % 8;
    int m = 0;
    for (int i = 0; i < 6; ++i)
        if ((sigpow6(1 << i, tt) >> j) & 1) m |= 1 << i;
    return m;
}

// ---- cross-lane xor helpers (DPP / ds_swizzle / permlane32_swap) ----------
template<int C>
__device__ __forceinline__ float dppf(float x) {
    return __int_as_float(__builtin_amdgcn_mov_dpp(__float_as_int(x), C, 0xF, 0xF, true));
}

template<int M>
__device__ __forceinline__ float shx(float x) {
    static_assert(M > 0 && M < 64, "mask");
    constexpr int lo = M & 31;
    float y = x;
    if constexpr (lo == 1)       y = dppf<0xB1>(y);          // quad_perm [1,0,3,2]
    else if constexpr (lo == 2)  y = dppf<0x4E>(y);          // quad_perm [2,3,0,1]
    else if constexpr (lo == 3)  y = dppf<0x1B>(y);          // quad_perm [3,2,1,0]
    else if constexpr (lo == 7)  y = dppf<0x141>(y);         // row_half_mirror
    else if constexpr (lo == 15) y = dppf<0x140>(y);         // row_mirror
    else if constexpr (lo != 0)
        y = __int_as_float(__builtin_amdgcn_ds_swizzle(__float_as_int(y),
                                                       0x1F | (lo << 10)));
    if constexpr ((M & 32) != 0) {
        int yi = __float_as_int(y);
        auto p = __builtin_amdgcn_permlane32_swap(yi, yi, false, false);
        y = (__int_as_float(p[0]) + __int_as_float(p[1])) - y;
    }
    return y;
}

__device__ __forceinline__ float wave_sum(float x) {
    x += dppf<0xB1>(x);
    x += dppf<0x4E>(x);
    x += __int_as_float(__builtin_amdgcn_ds_swizzle(__float_as_int(x), 0x1F | (4 << 10)));
    x += __int_as_float(__builtin_amdgcn_ds_swizzle(__float_as_int(x), 0x1F | (8 << 10)));
    x += __int_as_float(__builtin_amdgcn_ds_swizzle(__float_as_int(x), 0x1F | (16 << 10)));
    int xi = __float_as_int(x);
    auto p = __builtin_amdgcn_permlane32_swap(xi, xi, false, false);
    return __int_as_float(p[0]) + __int_as_float(p[1]);
}

// pin the whole state to arch VGPRs at this program point
__device__ __forceinline__ void pin(float* v) {
    #pragma unroll
    for (int r = 0; r < 64; ++r) asm volatile("" : "+v"(v[r]));
}

// ---- gate building blocks (T = completed ring layers) ---------------------
template<int T, int Q>   // tan-form RY on reg qubit Q (2 fma per pair)
__device__ __forceinline__ void regRY(float* v, float t) {
    constexpr int D = sigpow6(1 << Q, T);
    #pragma unroll
    for (int r0 = 0; r0 < 64; ++r0) {
        if (r0 & (1 << Q)) continue;
        const int p0 = sigpow6(r0, T);
        const int p1 = p0 ^ D;
        float a0 = v[p0], a1 = v[p1];
        v[p0] = fmaf(t, -a1, a0);
        v[p1] = fmaf(t,  a0, a1);
    }
}

template<int T, int J>   // tan-form RY on lane qubit 6+J (shuffle + 1 fma)
__device__ __forceinline__ void laneRY(float* v, float t, int lane) {
    constexpr int M  = sigpow6(1 << J, T);
    constexpr int RM = rowmask6(J, T);
    const float ts = (__popc(lane & RM) & 1) ? t : -t;
    #pragma unroll
    for (int r = 0; r < 64; ++r) {
        float o = shx<M>(v[r]);
        v[r] = fmaf(ts, o, v[r]);
    }
}

template<int T>          // CNOT(5,6): reg bit5 controls lane xor
__device__ __forceinline__ void c56(float* v) {
    constexpr int ML = sigpow6(1, T);
    #pragma unroll
    for (int r = 32; r < 64; ++r) {
        const int pr = sigpow6(r, T + 1);
        v[pr] = shx<ML>(v[pr]);
    }
}

template<int T>          // CNOT(11,0): lane bit5 controls reg-bit0 swap
__device__ __forceinline__ void c110(float* v, int lane) {
    const bool cond = (__popc(lane & rowmask6(5, T + 1)) & 1) != 0;
    constexpr int D = sigpow6(1, T + 1);
    #pragma unroll
    for (int r = 0; r < 64; r += 2) {
        const int a0 = sigpow6(r, T + 1);
        const int a1 = a0 ^ D;
        float x0 = v[a0], x1 = v[a1];
        v[a0] = cond ? x1 : x0;
        v[a1] = cond ? x0 : x1;
    }
}

__device__ __forceinline__ float tanhalf(float ang, float& G) {
    float s, c;
    __sincosf(ang, &s, &c);
    G *= c;
    return s * __builtin_amdgcn_rcpf(c);
}

template<int T>
__device__ __forceinline__ void do_layer(float* v, const float* __restrict__ th,
                                         int lane, float& G) {
    regRY<T, 0>(v, tanhalf(0.5f * th[T * NQ + 0], G));
    regRY<T, 1>(v, tanhalf(0.5f * th[T * NQ + 1], G));
    regRY<T, 2>(v, tanhalf(0.5f * th[T * NQ + 2], G));
    regRY<T, 3>(v, tanhalf(0.5f * th[T * NQ + 3], G));
    regRY<T, 4>(v, tanhalf(0.5f * th[T * NQ + 4], G));
    regRY<T, 5>(v, tanhalf(0.5f * th[T * NQ + 5], G));
    laneRY<T, 0>(v, tanhalf(0.5f * th[T * NQ + 6],  G), lane);
    laneRY<T, 1>(v, tanhalf(0.5f * th[T * NQ + 7],  G), lane);
    laneRY<T, 2>(v, tanhalf(0.5f * th[T * NQ + 8],  G), lane);
    laneRY<T, 3>(v, tanhalf(0.5f * th[T * NQ + 9],  G), lane);
    laneRY<T, 4>(v, tanhalf(0.5f * th[T * NQ + 10], G), lane);
    laneRY<T, 5>(v, tanhalf(0.5f * th[T * NQ + 11], G), lane);
    c56<T>(v);
    c110<T>(v, lane);
    pin(v);
}

__global__ __attribute__((amdgpu_flat_work_group_size(256, 256),
                          amdgpu_waves_per_eu(2)))
void qc_kernel(const float* __restrict__ x, const float* __restrict__ theta,
               float* __restrict__ out) {
    const int lane = threadIdx.x & 63;
    const int b = (blockIdx.x << 2) + (threadIdx.x >> 6);

    float v[64];

    // ---- initial product state (exact s,c form; per-batch angles)
    float L = 1.0f;
    #pragma unroll
    for (int q = 6; q < NQ; ++q) {
        float s, c;
        __sincosf(0.5f * x[b * NQ + q], &s, &c);
        L *= ((lane >> (q - 6)) & 1) ? s : c;
    }
    v[0] = L;
    #pragma unroll
    for (int q = 0; q < 6; ++q) {
        float s, c;
        __sincosf(0.5f * x[b * NQ + q], &s, &c);
        #pragma unroll
        for (int r = 0; r < (1 << q); ++r) {
            v[r + (1 << q)] = v[r] * s;
            v[r]            = v[r] * c;
        }
    }
    pin(v);

    float G = 1.0f;   // deferred product of 48 cosines
    do_layer<0>(v, theta, lane, G);
    do_layer<1>(v, theta, lane, G);
    do_layer<2>(v, theta, lane, G);
    do_layer<3>(v, theta, lane, G);

    // ---- epilogue: out[b,q] = G^2 * sum_d v[d]^2 * (1 - 2*bit_q(d))
    // logical reg index L lives at phys index L ^ ((L&3)<<4)  (= sig^4)
    #pragma unroll
    for (int r = 0; r < 64; ++r) v[r] *= v[r];

    float Dq[6];
    float s1[32];
    {
        float d = 0.f;
        #pragma unroll
        for (int k = 0; k < 32; ++k) {
            const int i0 = (2 * k)     ^ (((2 * k)     & 3) << 4);
            const int i1 = (2 * k + 1) ^ (((2 * k + 1) & 3) << 4);
            s1[k] = v[i0] + v[i1];
            d    += v[i0] - v[i1];
        }
        Dq[0] = d;
    }
    #pragma unroll
    for (int j = 1; j < 6; ++j) {
        const int n = 32 >> j;
        float d = 0.f;
        #pragma unroll
        for (int k = 0; k < n; ++k) {
            d    += s1[2 * k] - s1[2 * k + 1];
            s1[k] = s1[2 * k] + s1[2 * k + 1];
        }
        Dq[j] = d;
    }
    float tot = s1[0];

    const float G2 = G * G;
    tot *= G2;
    #pragma unroll
    for (int j = 0; j < 6; ++j) Dq[j] *= G2;

    float res[NQ];
    #pragma unroll
    for (int j = 0; j < 6; ++j) res[j] = wave_sum(Dq[j]);
    #pragma unroll
    for (int j = 0; j < 6; ++j) {
        const bool bit = (__popc(lane & rowmask6(j, 4)) & 1) != 0;
        res[6 + j] = wave_sum(bit ? -tot : tot);
    }

    float myres = res[0];
    #pragma unroll
    for (int q = 1; q < NQ; ++q) myres = (lane == q) ? res[q] : myres;
    if (lane < NQ) out[b * NQ + lane] = myres;
}

extern "C" void kernel_launch(void* const* d_in, const int* in_sizes, int n_in,
                              void* d_out, int out_size, void* d_ws, size_t ws_size,
                              hipStream_t stream) {
    const float* x     = (const float*)d_in[0];
    const float* theta = (const float*)d_in[1];
    float* out = (float*)d_out;
    dim3 grid(BATCH / 4), block(256);
    qc_kernel<<<grid, block, 0, stream>>>(x, theta, out);
}

// Round 6
// 69.342 us; speedup vs baseline: 1.4451x; 1.4451x over previous
//
#include <hip/hip_runtime.h>

#define NQ    12
#define BATCH 8192

// ---------------------------------------------------------------------------
// One wave = one batch element's 4096-dim real state (imag is identically 0).
// Two layouts:
//   A: lane bits = qubits 6..11, reg bits = qubits 0..5
//   B: lane bits = qubits 0..5,  reg bits = qubits 6..11
// All 12 RYs of a layer commute -> apply 6 reg-gates, transpose (per-wave LDS,
// no barrier), apply the other 6 as reg-gates, then the ring permutation in
// the current layout. Ring renamings (sig/rho powers) swap roles at each
// transpose; boundary CNOTs are explicit. Layer 0 folds into the init
// product state: RY(th)RY(x)|0> = RY(th+x)|0>.
// RY in tan form: amplitude scale G = prod cos folded into epilogue as G^2.
// ---------------------------------------------------------------------------

constexpr int sig6(int x)            { return (x ^ (x << 1)) & 63; }
constexpr int sigpow6(int x, int t)  { return t == 0 ? x : sigpow6(sig6(x), t - 1); }
// bit_j(sig^-t(p)) = parity(p & rowmask6(j,t));  sig^8 = I
constexpr int rowmask6(int j, int t) {
    int tt = (8 - (t % 8)) % 8;
    int m = 0;
    for (int i = 0; i < 6; ++i)
        if ((sigpow6(1 << i, tt) >> j) & 1) m |= 1 << i;
    return m;
}

// ---- cross-lane helpers (used sparingly now) ------------------------------
template<int C>
__device__ __forceinline__ float dppf(float x) {
    return __int_as_float(__builtin_amdgcn_mov_dpp(__float_as_int(x), C, 0xF, 0xF, true));
}

template<int M>
__device__ __forceinline__ float shx(float x) {
    static_assert(M > 0 && M < 64, "mask");
    constexpr int lo = M & 31;
    float y = x;
    if constexpr (lo == 1)       y = dppf<0xB1>(y);          // quad_perm [1,0,3,2]
    else if constexpr (lo == 2)  y = dppf<0x4E>(y);          // quad_perm [2,3,0,1]
    else if constexpr (lo == 3)  y = dppf<0x1B>(y);          // quad_perm [3,2,1,0]
    else if constexpr (lo == 7)  y = dppf<0x141>(y);         // row_half_mirror
    else if constexpr (lo == 15) y = dppf<0x140>(y);         // row_mirror
    else if constexpr (lo != 0)
        y = __int_as_float(__builtin_amdgcn_ds_swizzle(__float_as_int(y),
                                                       0x1F | (lo << 10)));
    if constexpr ((M & 32) != 0) {
        int yi = __float_as_int(y);
        auto p = __builtin_amdgcn_permlane32_swap(yi, yi, false, false);
        y = (__int_as_float(p[0]) + __int_as_float(p[1])) - y;
    }
    return y;
}

__device__ __forceinline__ float wave_sum(float x) {
    x += dppf<0xB1>(x);
    x += dppf<0x4E>(x);
    x += __int_as_float(__builtin_amdgcn_ds_swizzle(__float_as_int(x), 0x1F | (4 << 10)));
    x += __int_as_float(__builtin_amdgcn_ds_swizzle(__float_as_int(x), 0x1F | (8 << 10)));
    x += __int_as_float(__builtin_amdgcn_ds_swizzle(__float_as_int(x), 0x1F | (16 << 10)));
    int xi = __float_as_int(x);
    auto p = __builtin_amdgcn_permlane32_swap(xi, xi, false, false);
    return __int_as_float(p[0]) + __int_as_float(p[1]);
}

// ---- gates ---------------------------------------------------------------
template<int T, int Q>   // tan-form RY on current reg qubit-bit Q, renaming sig^T
__device__ __forceinline__ void regRY(float* v, float t) {
    constexpr int D = sigpow6(1 << Q, T);
    #pragma unroll
    for (int r0 = 0; r0 < 64; ++r0) {
        if (r0 & (1 << Q)) continue;
        const int p0 = sigpow6(r0, T);
        const int p1 = p0 ^ D;
        float a0 = v[p0], a1 = v[p1];
        v[p0] = fmaf(t, -a1, a0);
        v[p1] = fmaf(t,  a0, a1);
    }
}

// ring boundary ops, layout A (reg = q0..5, lane = q6..11)
template<int T>          // CNOT(5,6): reg bit5 (advanced) controls lane xor
__device__ __forceinline__ void c56A(float* v) {
    constexpr int ML = sigpow6(1, T);        // lane power not yet advanced
    #pragma unroll
    for (int r = 32; r < 64; ++r) {
        const int pr = sigpow6(r, T + 1);    // reg power advanced
        v[pr] = shx<ML>(v[pr]);
    }
}
template<int T>          // CNOT(11,0): lane bit5 (advanced) controls reg-bit0 swap
__device__ __forceinline__ void c110A(float* v, int lane) {
    const bool cond = (__popc(lane & rowmask6(5, T + 1)) & 1) != 0;
    constexpr int D = sigpow6(1, T + 1);
    #pragma unroll
    for (int r0 = 0; r0 < 64; r0 += 2) {
        const int a0 = sigpow6(r0, T + 1);
        const int a1 = a0 ^ D;
        float x0 = v[a0], x1 = v[a1];
        v[a0] = cond ? x1 : x0;
        v[a1] = cond ? x0 : x1;
    }
}

// ring boundary ops, layout B (lane = q0..5, reg = q6..11)
template<int T>          // CNOT(5,6): lane bit5 (advanced) controls reg-bit0 swap
__device__ __forceinline__ void c56B(float* v, int lane) {
    const bool cond = (__popc(lane & rowmask6(5, T + 1)) & 1) != 0;
    constexpr int D = sigpow6(1, T);         // reg power not yet advanced
    #pragma unroll
    for (int r0 = 0; r0 < 64; r0 += 2) {
        const int a0 = sigpow6(r0, T);
        const int a1 = a0 ^ D;
        float x0 = v[a0], x1 = v[a1];
        v[a0] = cond ? x1 : x0;
        v[a1] = cond ? x0 : x1;
    }
}
template<int T>          // CNOT(11,0): reg bit5 (advanced) controls lane xor
__device__ __forceinline__ void c110B(float* v) {
    constexpr int ML = sigpow6(1, T + 1);    // lane power advanced
    #pragma unroll
    for (int r = 32; r < 64; ++r) {
        const int pr = sigpow6(r, T + 1);    // reg power advanced
        v[pr] = shx<ML>(v[pr]);
    }
}

template<int T>
__device__ __forceinline__ void ringA(float* v, int lane) { c56A<T>(v); c110A<T>(v, lane); }
template<int T>
__device__ __forceinline__ void ringB(float* v, int lane) { c56B<T>(v, lane); c110B<T>(v); }

// ---- lane<->reg transpose via per-wave padded LDS (no barrier needed) -----
__device__ __forceinline__ void transpose64(float* v, float* sh, int lane) {
    // write: cell(lane p, reg r) at p*65 + r  (per-lane base, imm offsets 0..63)
    #pragma unroll
    for (int r = 0; r < 64; ++r) sh[lane * 65 + r] = v[r];
    asm volatile("" ::: "memory");
    // read: v'[r'] = cell(p=r', r=lane) = r'*65 + lane  (stride 65 across regs)
    #pragma unroll
    for (int r = 0; r < 64; ++r) v[r] = sh[r * 65 + lane];
    asm volatile("" ::: "memory");
}

__device__ __forceinline__ float tanhalf(float ang, float& G) {
    float s, c;
    __sincosf(ang, &s, &c);
    G *= c;
    return s * __builtin_amdgcn_rcpf(c);
}

// layer entering in layout A (applies theta row T; ends in layout B)
template<int T>
__device__ __forceinline__ void layerA(float* v, const float* __restrict__ th,
                                       int lane, float& G, float* sh) {
    regRY<T, 0>(v, tanhalf(0.5f * th[T * NQ + 0], G));
    regRY<T, 1>(v, tanhalf(0.5f * th[T * NQ + 1], G));
    regRY<T, 2>(v, tanhalf(0.5f * th[T * NQ + 2], G));
    regRY<T, 3>(v, tanhalf(0.5f * th[T * NQ + 3], G));
    regRY<T, 4>(v, tanhalf(0.5f * th[T * NQ + 4], G));
    regRY<T, 5>(v, tanhalf(0.5f * th[T * NQ + 5], G));
    transpose64(v, sh, lane);                 // now layout B (reg = q6..11)
    regRY<T, 0>(v, tanhalf(0.5f * th[T * NQ + 6],  G));
    regRY<T, 1>(v, tanhalf(0.5f * th[T * NQ + 7],  G));
    regRY<T, 2>(v, tanhalf(0.5f * th[T * NQ + 8],  G));
    regRY<T, 3>(v, tanhalf(0.5f * th[T * NQ + 9],  G));
    regRY<T, 4>(v, tanhalf(0.5f * th[T * NQ + 10], G));
    regRY<T, 5>(v, tanhalf(0.5f * th[T * NQ + 11], G));
    ringB<T>(v, lane);
}

// layer entering in layout B (applies theta row T; ends in layout A)
template<int T>
__device__ __forceinline__ void layerB(float* v, const float* __restrict__ th,
                                       int lane, float& G, float* sh) {
    regRY<T, 0>(v, tanhalf(0.5f * th[T * NQ + 6],  G));
    regRY<T, 1>(v, tanhalf(0.5f * th[T * NQ + 7],  G));
    regRY<T, 2>(v, tanhalf(0.5f * th[T * NQ + 8],  G));
    regRY<T, 3>(v, tanhalf(0.5f * th[T * NQ + 9],  G));
    regRY<T, 4>(v, tanhalf(0.5f * th[T * NQ + 10], G));
    regRY<T, 5>(v, tanhalf(0.5f * th[T * NQ + 11], G));
    transpose64(v, sh, lane);                 // now layout A (reg = q0..5)
    regRY<T, 0>(v, tanhalf(0.5f * th[T * NQ + 0], G));
    regRY<T, 1>(v, tanhalf(0.5f * th[T * NQ + 1], G));
    regRY<T, 2>(v, tanhalf(0.5f * th[T * NQ + 2], G));
    regRY<T, 3>(v, tanhalf(0.5f * th[T * NQ + 3], G));
    regRY<T, 4>(v, tanhalf(0.5f * th[T * NQ + 4], G));
    regRY<T, 5>(v, tanhalf(0.5f * th[T * NQ + 5], G));
    ringA<T>(v, lane);
}

__global__ __launch_bounds__(128)
void qc_kernel(const float* __restrict__ x, const float* __restrict__ theta,
               float* __restrict__ out) {
    __shared__ float shbuf[2][64 * 65];
    const int lane = threadIdx.x & 63;
    const int wid  = threadIdx.x >> 6;
    const int b = (blockIdx.x << 1) + wid;
    float* sh = &shbuf[wid][0];

    float v[64];

    // ---- init in layout A, with layer-0 thetas folded in:
    // RY(th0q) RY(xq) |0> = RY(xq + th0q) |0>
    float L = 1.0f;
    #pragma unroll
    for (int q = 6; q < NQ; ++q) {
        float s, c;
        __sincosf(0.5f * (x[b * NQ + q] + theta[q]), &s, &c);
        L *= ((lane >> (q - 6)) & 1) ? s : c;
    }
    v[0] = L;
    #pragma unroll
    for (int q = 0; q < 6; ++q) {
        float s, c;
        __sincosf(0.5f * (x[b * NQ + q] + theta[q]), &s, &c);
        #pragma unroll
        for (int r = 0; r < (1 << q); ++r) {
            v[r + (1 << q)] = v[r] * s;
            v[r]            = v[r] * c;
        }
    }

    float G = 1.0f;            // product of cosines over layers 1..3 (36 gates)
    ringA<0>(v, lane);         // layer-0 ring (gates folded into init)
    layerA<1>(v, theta, lane, G, sh);   // A -> B
    layerB<2>(v, theta, lane, G, sh);   // B -> A
    layerA<3>(v, theta, lane, G, sh);   // A -> B
    // final state: layout B, renaming powers (4,4)

    // ---- epilogue in layout B: out[b,q] = G^2 * sum_d v[d]^2 * (1-2 bit_q(d))
    // logical reg index Lr at phys Lr ^ ((Lr&3)<<4) (= sig^4); regs hold q6..11
    #pragma unroll
    for (int r = 0; r < 64; ++r) v[r] *= v[r];

    float Dq[6];
    float s1[32];
    {
        float d = 0.f;
        #pragma unroll
        for (int k = 0; k < 32; ++k) {
            const int i0 = (2 * k)     ^ (((2 * k)     & 3) << 4);
            const int i1 = (2 * k + 1) ^ (((2 * k + 1) & 3) << 4);
            s1[k] = v[i0] + v[i1];
            d    += v[i0] - v[i1];
        }
        Dq[0] = d;
    }
    #pragma unroll
    for (int j = 1; j < 6; ++j) {
        const int n = 32 >> j;
        float d = 0.f;
        #pragma unroll
        for (int k = 0; k < n; ++k) {
            d    += s1[2 * k] - s1[2 * k + 1];
            s1[k] = s1[2 * k] + s1[2 * k + 1];
        }
        Dq[j] = d;
    }
    float tot = s1[0];

    const float G2 = G * G;
    tot *= G2;
    #pragma unroll
    for (int j = 0; j < 6; ++j) Dq[j] *= G2;

    float res[NQ];
    #pragma unroll
    for (int j = 0; j < 6; ++j) res[6 + j] = wave_sum(Dq[j]);   // qubits 6..11 (regs)
    #pragma unroll
    for (int j = 0; j < 6; ++j) {                               // qubits 0..5 (lanes)
        const bool bit = (__popc(lane & rowmask6(j, 4)) & 1) != 0;
        res[j] = wave_sum(bit ? -tot : tot);
    }

    float myres = res[0];
    #pragma unroll
    for (int q = 1; q < NQ; ++q) myres = (lane == q) ? res[q] : myres;
    if (lane < NQ) out[b * NQ + lane] = myres;
}

extern "C" void kernel_launch(void* const* d_in, const int* in_sizes, int n_in,
                              void* d_out, int out_size, void* d_ws, size_t ws_size,
                              hipStream_t stream) {
    const float* x     = (const float*)d_in[0];
    const float* theta = (const float*)d_in[1];
    float* out = (float*)d_out;
    dim3 grid(BATCH / 2), block(128);
    qc_kernel<<<grid, block, 0, stream>>>(x, theta, out);
}

// Round 7
// 62.883 us; speedup vs baseline: 1.5935x; 1.1027x over previous
//
#include <hip/hip_runtime.h>

#define NQ    12
#define BATCH 8192

// ---------------------------------------------------------------------------
// One wave = one batch element's 4096-dim real state (imag is identically 0).
// Two layouts:
//   A: lane bits = qubits 6..11, reg bits = qubits 0..5
//   B: lane bits = qubits 0..5,  reg bits = qubits 6..11
// All 12 RYs of a layer commute -> apply 6 reg-gates, transpose (per-wave LDS,
// no barrier), apply the other 6 as reg-gates, then the ring permutation in
// the current layout. Ring renamings (sig/rho powers) swap roles at each
// transpose; boundary CNOTs are explicit. Layer 0 folds into the init
// product state: RY(th)RY(x)|0> = RY(th+x)|0>.
// RY in tan form: amplitude scale G = prod cos folded into epilogue as G^2.
//
// This round: 2-phase lane-split transpose in a 32x68 buffer (8.7 KB/wave,
// was 16.6) -> 16 waves/CU instead of 8; b128-vectorized transpose writes.
// ---------------------------------------------------------------------------

constexpr int sig6(int x)            { return (x ^ (x << 1)) & 63; }
constexpr int sigpow6(int x, int t)  { return t == 0 ? x : sigpow6(sig6(x), t - 1); }
// bit_j(sig^-t(p)) = parity(p & rowmask6(j,t));  sig^8 = I
constexpr int rowmask6(int j, int t) {
    int tt = (8 - (t % 8)) % 8;
    int m = 0;
    for (int i = 0; i < 6; ++i)
        if ((sigpow6(1 << i, tt) >> j) & 1) m |= 1 << i;
    return m;
}

// ---- cross-lane helpers (used sparingly) ----------------------------------
template<int C>
__device__ __forceinline__ float dppf(float x) {
    return __int_as_float(__builtin_amdgcn_mov_dpp(__float_as_int(x), C, 0xF, 0xF, true));
}

template<int M>
__device__ __forceinline__ float shx(float x) {
    static_assert(M > 0 && M < 64, "mask");
    constexpr int lo = M & 31;
    float y = x;
    if constexpr (lo == 1)       y = dppf<0xB1>(y);          // quad_perm [1,0,3,2]
    else if constexpr (lo == 2)  y = dppf<0x4E>(y);          // quad_perm [2,3,0,1]
    else if constexpr (lo == 3)  y = dppf<0x1B>(y);          // quad_perm [3,2,1,0]
    else if constexpr (lo == 7)  y = dppf<0x141>(y);         // row_half_mirror
    else if constexpr (lo == 15) y = dppf<0x140>(y);         // row_mirror
    else if constexpr (lo != 0)
        y = __int_as_float(__builtin_amdgcn_ds_swizzle(__float_as_int(y),
                                                       0x1F | (lo << 10)));
    if constexpr ((M & 32) != 0) {
        int yi = __float_as_int(y);
        auto p = __builtin_amdgcn_permlane32_swap(yi, yi, false, false);
        y = (__int_as_float(p[0]) + __int_as_float(p[1])) - y;
    }
    return y;
}

__device__ __forceinline__ float wave_sum(float x) {
    x += dppf<0xB1>(x);
    x += dppf<0x4E>(x);
    x += __int_as_float(__builtin_amdgcn_ds_swizzle(__float_as_int(x), 0x1F | (4 << 10)));
    x += __int_as_float(__builtin_amdgcn_ds_swizzle(__float_as_int(x), 0x1F | (8 << 10)));
    x += __int_as_float(__builtin_amdgcn_ds_swizzle(__float_as_int(x), 0x1F | (16 << 10)));
    int xi = __float_as_int(x);
    auto p = __builtin_amdgcn_permlane32_swap(xi, xi, false, false);
    return __int_as_float(p[0]) + __int_as_float(p[1]);
}

// ---- gates ---------------------------------------------------------------
template<int T, int Q>   // tan-form RY on current reg qubit-bit Q, renaming sig^T
__device__ __forceinline__ void regRY(float* v, float t) {
    constexpr int D = sigpow6(1 << Q, T);
    #pragma unroll
    for (int r0 = 0; r0 < 64; ++r0) {
        if (r0 & (1 << Q)) continue;
        const int p0 = sigpow6(r0, T);
        const int p1 = p0 ^ D;
        float a0 = v[p0], a1 = v[p1];
        v[p0] = fmaf(t, -a1, a0);
        v[p1] = fmaf(t,  a0, a1);
    }
}

// ring boundary ops, layout A (reg = q0..5, lane = q6..11)
template<int T>          // CNOT(5,6): reg bit5 (advanced) controls lane xor
__device__ __forceinline__ void c56A(float* v) {
    constexpr int ML = sigpow6(1, T);        // lane power not yet advanced
    #pragma unroll
    for (int r = 32; r < 64; ++r) {
        const int pr = sigpow6(r, T + 1);    // reg power advanced
        v[pr] = shx<ML>(v[pr]);
    }
}
template<int T>          // CNOT(11,0): lane bit5 (advanced) controls reg-bit0 swap
__device__ __forceinline__ void c110A(float* v, int lane) {
    const bool cond = (__popc(lane & rowmask6(5, T + 1)) & 1) != 0;
    constexpr int D = sigpow6(1, T + 1);
    #pragma unroll
    for (int r0 = 0; r0 < 64; r0 += 2) {
        const int a0 = sigpow6(r0, T + 1);
        const int a1 = a0 ^ D;
        float x0 = v[a0], x1 = v[a1];
        v[a0] = cond ? x1 : x0;
        v[a1] = cond ? x0 : x1;
    }
}

// ring boundary ops, layout B (lane = q0..5, reg = q6..11)
template<int T>          // CNOT(5,6): lane bit5 (advanced) controls reg-bit0 swap
__device__ __forceinline__ void c56B(float* v, int lane) {
    const bool cond = (__popc(lane & rowmask6(5, T + 1)) & 1) != 0;
    constexpr int D = sigpow6(1, T);         // reg power not yet advanced
    #pragma unroll
    for (int r0 = 0; r0 < 64; r0 += 2) {
        const int a0 = sigpow6(r0, T);
        const int a1 = a0 ^ D;
        float x0 = v[a0], x1 = v[a1];
        v[a0] = cond ? x1 : x0;
        v[a1] = cond ? x0 : x1;
    }
}
template<int T>          // CNOT(11,0): reg bit5 (advanced) controls lane xor
__device__ __forceinline__ void c110B(float* v) {
    constexpr int ML = sigpow6(1, T + 1);    // lane power advanced
    #pragma unroll
    for (int r = 32; r < 64; ++r) {
        const int pr = sigpow6(r, T + 1);    // reg power advanced
        v[pr] = shx<ML>(v[pr]);
    }
}

template<int T>
__device__ __forceinline__ void ringA(float* v, int lane) { c56A<T>(v); c110A<T>(v, lane); }
template<int T>
__device__ __forceinline__ void ringB(float* v, int lane) { c56B<T>(v, lane); c110B<T>(v); }

// ---- lane<->reg transpose, 2-phase lane-split, 32x68 buffer ---------------
// new[l][r'] = old[r'][l].  Phase 1: old lanes 0..31 publish all 64 regs
// (rows 0..31), every lane reads its new regs 0..31 (old lanes 0..31).
// Phase 2: old lanes 32..63 publish (same rows), every lane reads regs 32..63.
// Same-wave DS ops are processed in order -> no barrier needed.
// Row stride 68 floats: 16B-aligned rows (b128 writes), 2-way-free b32 reads.
__device__ __forceinline__ void transpose64(float* v, float* sh, int lane) {
    const int row = lane & 31;
    if (lane < 32) {
        #pragma unroll
        for (int r = 0; r < 64; r += 4)
            *reinterpret_cast<float4*>(&sh[row * 68 + r]) =
                make_float4(v[r], v[r + 1], v[r + 2], v[r + 3]);
    }
    asm volatile("" ::: "memory");
    float nv[32];
    #pragma unroll
    for (int r = 0; r < 32; ++r) nv[r] = sh[r * 68 + lane];
    asm volatile("" ::: "memory");
    if (lane >= 32) {
        #pragma unroll
        for (int r = 0; r < 64; r += 4)
            *reinterpret_cast<float4*>(&sh[row * 68 + r]) =
                make_float4(v[r], v[r + 1], v[r + 2], v[r + 3]);
    }
    asm volatile("" ::: "memory");
    #pragma unroll
    for (int r = 0; r < 32; ++r) v[32 + r] = sh[r * 68 + lane];
    #pragma unroll
    for (int r = 0; r < 32; ++r) v[r] = nv[r];
    asm volatile("" ::: "memory");
}

__device__ __forceinline__ float tanhalf(float ang, float& G) {
    float s, c;
    __sincosf(ang, &s, &c);
    G *= c;
    return s * __builtin_amdgcn_rcpf(c);
}

// layer entering in layout A (applies theta row T; ends in layout B)
template<int T>
__device__ __forceinline__ void layerA(float* v, const float* __restrict__ th,
                                       int lane, float& G, float* sh) {
    regRY<T, 0>(v, tanhalf(0.5f * th[T * NQ + 0], G));
    regRY<T, 1>(v, tanhalf(0.5f * th[T * NQ + 1], G));
    regRY<T, 2>(v, tanhalf(0.5f * th[T * NQ + 2], G));
    regRY<T, 3>(v, tanhalf(0.5f * th[T * NQ + 3], G));
    regRY<T, 4>(v, tanhalf(0.5f * th[T * NQ + 4], G));
    regRY<T, 5>(v, tanhalf(0.5f * th[T * NQ + 5], G));
    transpose64(v, sh, lane);                 // now layout B (reg = q6..11)
    regRY<T, 0>(v, tanhalf(0.5f * th[T * NQ + 6],  G));
    regRY<T, 1>(v, tanhalf(0.5f * th[T * NQ + 7],  G));
    regRY<T, 2>(v, tanhalf(0.5f * th[T * NQ + 8],  G));
    regRY<T, 3>(v, tanhalf(0.5f * th[T * NQ + 9],  G));
    regRY<T, 4>(v, tanhalf(0.5f * th[T * NQ + 10], G));
    regRY<T, 5>(v, tanhalf(0.5f * th[T * NQ + 11], G));
    ringB<T>(v, lane);
}

// layer entering in layout B (applies theta row T; ends in layout A)
template<int T>
__device__ __forceinline__ void layerB(float* v, const float* __restrict__ th,
                                       int lane, float& G, float* sh) {
    regRY<T, 0>(v, tanhalf(0.5f * th[T * NQ + 6],  G));
    regRY<T, 1>(v, tanhalf(0.5f * th[T * NQ + 7],  G));
    regRY<T, 2>(v, tanhalf(0.5f * th[T * NQ + 8],  G));
    regRY<T, 3>(v, tanhalf(0.5f * th[T * NQ + 9],  G));
    regRY<T, 4>(v, tanhalf(0.5f * th[T * NQ + 10], G));
    regRY<T, 5>(v, tanhalf(0.5f * th[T * NQ + 11], G));
    transpose64(v, sh, lane);                 // now layout A (reg = q0..5)
    regRY<T, 0>(v, tanhalf(0.5f * th[T * NQ + 0], G));
    regRY<T, 1>(v, tanhalf(0.5f * th[T * NQ + 1], G));
    regRY<T, 2>(v, tanhalf(0.5f * th[T * NQ + 2], G));
    regRY<T, 3>(v, tanhalf(0.5f * th[T * NQ + 3], G));
    regRY<T, 4>(v, tanhalf(0.5f * th[T * NQ + 4], G));
    regRY<T, 5>(v, tanhalf(0.5f * th[T * NQ + 5], G));
    ringA<T>(v, lane);
}

__global__ __launch_bounds__(128)
void qc_kernel(const float* __restrict__ x, const float* __restrict__ theta,
               float* __restrict__ out) {
    __shared__ float shbuf[2][32 * 68];
    const int lane = threadIdx.x & 63;
    const int wid  = threadIdx.x >> 6;
    const int b = (blockIdx.x << 1) + wid;
    float* sh = &shbuf[wid][0];

    float v[64];

    // ---- init in layout A, with layer-0 thetas folded in:
    // RY(th0q) RY(xq) |0> = RY(xq + th0q) |0>
    float L = 1.0f;
    #pragma unroll
    for (int q = 6; q < NQ; ++q) {
        float s, c;
        __sincosf(0.5f * (x[b * NQ + q] + theta[q]), &s, &c);
        L *= ((lane >> (q - 6)) & 1) ? s : c;
    }
    v[0] = L;
    #pragma unroll
    for (int q = 0; q < 6; ++q) {
        float s, c;
        __sincosf(0.5f * (x[b * NQ + q] + theta[q]), &s, &c);
        #pragma unroll
        for (int r = 0; r < (1 << q); ++r) {
            v[r + (1 << q)] = v[r] * s;
            v[r]            = v[r] * c;
        }
    }

    float G = 1.0f;            // product of cosines over layers 1..3 (36 gates)
    ringA<0>(v, lane);         // layer-0 ring (gates folded into init)
    layerA<1>(v, theta, lane, G, sh);   // A -> B
    layerB<2>(v, theta, lane, G, sh);   // B -> A
    layerA<3>(v, theta, lane, G, sh);   // A -> B
    // final state: layout B, renaming powers (4,4)

    // ---- epilogue in layout B: out[b,q] = G^2 * sum_d v[d]^2 * (1-2 bit_q(d))
    // logical reg index Lr at phys Lr ^ ((Lr&3)<<4) (= sig^4); regs hold q6..11
    #pragma unroll
    for (int r = 0; r < 64; ++r) v[r] *= v[r];

    float Dq[6];
    float s1[32];
    {
        float d = 0.f;
        #pragma unroll
        for (int k = 0; k < 32; ++k) {
            const int i0 = (2 * k)     ^ (((2 * k)     & 3) << 4);
            const int i1 = (2 * k + 1) ^ (((2 * k + 1) & 3) << 4);
            s1[k] = v[i0] + v[i1];
            d    += v[i0] - v[i1];
        }
        Dq[0] = d;
    }
    #pragma unroll
    for (int j = 1; j < 6; ++j) {
        const int n = 32 >> j;
        float d = 0.f;
        #pragma unroll
        for (int k = 0; k < n; ++k) {
            d    += s1[2 * k] - s1[2 * k + 1];
            s1[k] = s1[2 * k] + s1[2 * k + 1];
        }
        Dq[j] = d;
    }
    float tot = s1[0];

    const float G2 = G * G;
    tot *= G2;
    #pragma unroll
    for (int j = 0; j < 6; ++j) Dq[j] *= G2;

    float res[NQ];
    #pragma unroll
    for (int j = 0; j < 6; ++j) res[6 + j] = wave_sum(Dq[j]);   // qubits 6..11 (regs)
    #pragma unroll
    for (int j = 0; j < 6; ++j) {                               // qubits 0..5 (lanes)
        const bool bit = (__popc(lane & rowmask6(j, 4)) & 1) != 0;
        res[j] = wave_sum(bit ? -tot : tot);
    }

    float myres = res[0];
    #pragma unroll
    for (int q = 1; q < NQ; ++q) myres = (lane == q) ? res[q] : myres;
    if (lane < NQ) out[b * NQ + lane] = myres;
}

extern "C" void kernel_launch(void* const* d_in, const int* in_sizes, int n_in,
                              void* d_out, int out_size, void* d_ws, size_t ws_size,
                              hipStream_t stream) {
    const float* x     = (const float*)d_in[0];
    const float* theta = (const float*)d_in[1];
    float* out = (float*)d_out;
    dim3 grid(BATCH / 2), block(128);
    qc_kernel<<<grid, block, 0, stream>>>(x, theta, out);
}

// Round 8
// 46.580 us; speedup vs baseline: 2.1513x; 1.3500x over previous
//
#include <hip/hip_runtime.h>

#define NQ    12
#define BATCH 8192

typedef float v2f __attribute__((ext_vector_type(2)));

// ---------------------------------------------------------------------------
// One wave = one batch element's 4096-dim real state (imag identically 0).
// Layout A: lane bits = qubits 6..11, reg bits = qubits 0..5
// Layout B: lane bits = qubits 0..5,  reg bits = qubits 6..11
// Per layer: 6 reg-gates, LDS transpose, 6 reg-gates, ring boundary CNOTs;
// ring renamings (sig powers) deferred via compile-time index renaming.
// RY in tan form (G = prod cos folded into epilogue as G^2).
// This round: state as float2[32]; gates via packed v_pk_fma_f32 (sig
// preserves bit0 -> all Q>=1 gates pair float2s componentwise; Q==0 pairs
// comp-swapped float2s). 2304 scalar fma -> 576 pk_fma.
// ---------------------------------------------------------------------------

constexpr int sig6(int x)            { return (x ^ (x << 1)) & 63; }
constexpr int sigpow6(int x, int t)  { return t == 0 ? x : sigpow6(sig6(x), t - 1); }
constexpr int rowmask6(int j, int t) {        // bit_j(sig^-t(p)) = par(p & m)
    int tt = (8 - (t % 8)) % 8;
    int m = 0;
    for (int i = 0; i < 6; ++i)
        if ((sigpow6(1 << i, tt) >> j) & 1) m |= 1 << i;
    return m;
}
constexpr bool par6(int x) { return (__builtin_popcount(x & 63) & 1) != 0; }

#define VAT(w, i) w[(i) >> 1][(i) & 1]

// ---- cross-lane helpers ---------------------------------------------------
template<int C>
__device__ __forceinline__ float dppf(float x) {
    return __int_as_float(__builtin_amdgcn_mov_dpp(__float_as_int(x), C, 0xF, 0xF, true));
}

template<int M>
__device__ __forceinline__ float shx(float x) {
    static_assert(M > 0 && M < 64, "mask");
    constexpr int lo = M & 31;
    float y = x;
    if constexpr (lo == 1)       y = dppf<0xB1>(y);
    else if constexpr (lo == 2)  y = dppf<0x4E>(y);
    else if constexpr (lo == 3)  y = dppf<0x1B>(y);
    else if constexpr (lo == 7)  y = dppf<0x141>(y);
    else if constexpr (lo == 15) y = dppf<0x140>(y);
    else if constexpr (lo != 0)
        y = __int_as_float(__builtin_amdgcn_ds_swizzle(__float_as_int(y),
                                                       0x1F | (lo << 10)));
    if constexpr ((M & 32) != 0) {
        int yi = __float_as_int(y);
        auto p = __builtin_amdgcn_permlane32_swap(yi, yi, false, false);
        y = (__int_as_float(p[0]) + __int_as_float(p[1])) - y;
    }
    return y;
}

// signed butterfly: returns sum_l (-1)^par(l&M) x_l, with per-lane sign
// (-1)^par(lane&M); all writing lanes (0..11) verified sign-positive.
template<int M>
__device__ __forceinline__ float wave_red(float x) {
    { float o = dppf<0xB1>(x); x = (M & 1)  ? x - o : x + o; }
    { float o = dppf<0x4E>(x); x = (M & 2)  ? x - o : x + o; }
    { float o = __int_as_float(__builtin_amdgcn_ds_swizzle(__float_as_int(x), 0x1F | (4  << 10))); x = (M & 4)  ? x - o : x + o; }
    { float o = __int_as_float(__builtin_amdgcn_ds_swizzle(__float_as_int(x), 0x1F | (8  << 10))); x = (M & 8)  ? x - o : x + o; }
    { float o = __int_as_float(__builtin_amdgcn_ds_swizzle(__float_as_int(x), 0x1F | (16 << 10))); x = (M & 16) ? x - o : x + o; }
    int xi = __float_as_int(x);
    auto p = __builtin_amdgcn_permlane32_swap(xi, xi, false, false);
    float s = __int_as_float(p[0]) + __int_as_float(p[1]);
    return (M & 32) ? (2.0f * x - s) : s;
}

// ---- packed tan-form RY on reg qubit-bit Q, renaming sig^T ----------------
template<int T, int Q>
__device__ __forceinline__ void regRY(v2f* w, float t) {
    constexpr int D = sigpow6(1 << Q, T);   // physical partner xor
    const v2f tMM = {-t, -t}, tPP = {t, t}, tMP = {-t, t}, tPM = {t, -t};
    if constexpr (Q == 0) {
        // bit0(D)=1: partner is comp-swapped float2 k^(D>>1); comp = gate row.
        constexpr int K = D >> 1;
        #pragma unroll
        for (int k = 0; k < 32; ++k) {
            const int k2 = k ^ K;
            if (k2 < k) continue;
            v2f a = w[k], b = w[k2];
            v2f sb = {b[1], b[0]}, sa = {a[1], a[0]};
            w[k]  = __builtin_elementwise_fma(tMP, sb, a);
            w[k2] = __builtin_elementwise_fma(tMP, sa, b);
        }
    } else {
        constexpr int K  = D >> 1;             // D even: comps aligned
        constexpr int RM = rowmask6(Q, T);
        #pragma unroll
        for (int k = 0; k < 32; ++k) {
            const int k2 = k ^ K;
            if (k2 < k) continue;
            const bool p = par6((2 * k) & RM); // gate-bit of comp0, side k
            if constexpr (RM & 1) {            // comps have opposite rows
                v2f a = w[k], b = w[k2];
                const v2f tk  = p ? tPM : tMP;
                const v2f tk2 = p ? tMP : tPM;
                w[k]  = __builtin_elementwise_fma(tk,  b, a);
                w[k2] = __builtin_elementwise_fma(tk2, a, b);
            } else {                           // both comps same row
                if (p) {
                    v2f a = w[k2], b = w[k];   // k2 is the bit=0 side
                    w[k2] = __builtin_elementwise_fma(tMM, b, a);
                    w[k]  = __builtin_elementwise_fma(tPP, a, b);
                } else {
                    v2f a = w[k], b = w[k2];
                    w[k]  = __builtin_elementwise_fma(tMM, b, a);
                    w[k2] = __builtin_elementwise_fma(tPP, a, b);
                }
            }
        }
    }
}

// ---- ring boundary CNOTs (element-wise, renamed indices) ------------------
template<int T>          // layout A CNOT(5,6): reg bit5 controls lane xor
__device__ __forceinline__ void c56A(v2f* w) {
    constexpr int ML = sigpow6(1, T);
    #pragma unroll
    for (int r = 32; r < 64; ++r) {
        const int pr = sigpow6(r, T + 1);
        VAT(w, pr) = shx<ML>(VAT(w, pr));
    }
}
template<int T>          // layout A CNOT(11,0): lane bit5 controls reg swap
__device__ __forceinline__ void c110A(v2f* w, int lane) {
    const bool cond = par6(lane & rowmask6(5, T + 1));
    constexpr int D = sigpow6(1, T + 1);
    #pragma unroll
    for (int r0 = 0; r0 < 64; r0 += 2) {
        const int a0 = sigpow6(r0, T + 1);
        const int a1 = a0 ^ D;
        float x0 = VAT(w, a0), x1 = VAT(w, a1);
        VAT(w, a0) = cond ? x1 : x0;
        VAT(w, a1) = cond ? x0 : x1;
    }
}
template<int T>          // layout B CNOT(5,6): lane bit5 controls reg swap
__device__ __forceinline__ void c56B(v2f* w, int lane) {
    const bool cond = par6(lane & rowmask6(5, T + 1));
    constexpr int D = sigpow6(1, T);
    #pragma unroll
    for (int r0 = 0; r0 < 64; r0 += 2) {
        const int a0 = sigpow6(r0, T);
        const int a1 = a0 ^ D;
        float x0 = VAT(w, a0), x1 = VAT(w, a1);
        VAT(w, a0) = cond ? x1 : x0;
        VAT(w, a1) = cond ? x0 : x1;
    }
}
template<int T>          // layout B CNOT(11,0): reg bit5 controls lane xor
__device__ __forceinline__ void c110B(v2f* w) {
    constexpr int ML = sigpow6(1, T + 1);
    #pragma unroll
    for (int r = 32; r < 64; ++r) {
        const int pr = sigpow6(r, T + 1);
        VAT(w, pr) = shx<ML>(VAT(w, pr));
    }
}
template<int T>
__device__ __forceinline__ void ringA(v2f* w, int lane) { c56A<T>(w); c110A<T>(w, lane); }
template<int T>
__device__ __forceinline__ void ringB(v2f* w, int lane) { c56B<T>(w, lane); c110B<T>(w); }

// ---- lane<->reg transpose, 2-phase lane-split, 32x68 buffer ---------------
__device__ __forceinline__ void transpose64(v2f* w, float* sh, int lane) {
    const int row = lane & 31;
    if (lane < 32) {
        #pragma unroll
        for (int j = 0; j < 16; ++j)
            *reinterpret_cast<float4*>(&sh[row * 68 + 4 * j]) =
                make_float4(w[2*j][0], w[2*j][1], w[2*j+1][0], w[2*j+1][1]);
    }
    asm volatile("" ::: "memory");
    v2f nv[16];
    #pragma unroll
    for (int r = 0; r < 32; ++r) nv[r >> 1][r & 1] = sh[r * 68 + lane];
    asm volatile("" ::: "memory");
    if (lane >= 32) {
        #pragma unroll
        for (int j = 0; j < 16; ++j)
            *reinterpret_cast<float4*>(&sh[row * 68 + 4 * j]) =
                make_float4(w[2*j][0], w[2*j][1], w[2*j+1][0], w[2*j+1][1]);
    }
    asm volatile("" ::: "memory");
    #pragma unroll
    for (int r = 0; r < 32; ++r) w[16 + (r >> 1)][r & 1] = sh[r * 68 + lane];
    #pragma unroll
    for (int k = 0; k < 16; ++k) w[k] = nv[k];
    asm volatile("" ::: "memory");
}

__device__ __forceinline__ float tanhalf(float ang, float& G) {
    float s, c;
    __sincosf(ang, &s, &c);
    G *= c;
    return s * __builtin_amdgcn_rcpf(c);
}

// layer entering in layout A (theta row T; ends in layout B)
template<int T>
__device__ __forceinline__ void layerA(v2f* w, const float* __restrict__ th,
                                       int lane, float& G, float* sh) {
    regRY<T, 0>(w, tanhalf(0.5f * th[T * NQ + 0], G));
    regRY<T, 1>(w, tanhalf(0.5f * th[T * NQ + 1], G));
    regRY<T, 2>(w, tanhalf(0.5f * th[T * NQ + 2], G));
    regRY<T, 3>(w, tanhalf(0.5f * th[T * NQ + 3], G));
    regRY<T, 4>(w, tanhalf(0.5f * th[T * NQ + 4], G));
    regRY<T, 5>(w, tanhalf(0.5f * th[T * NQ + 5], G));
    transpose64(w, sh, lane);
    regRY<T, 0>(w, tanhalf(0.5f * th[T * NQ + 6],  G));
    regRY<T, 1>(w, tanhalf(0.5f * th[T * NQ + 7],  G));
    regRY<T, 2>(w, tanhalf(0.5f * th[T * NQ + 8],  G));
    regRY<T, 3>(w, tanhalf(0.5f * th[T * NQ + 9],  G));
    regRY<T, 4>(w, tanhalf(0.5f * th[T * NQ + 10], G));
    regRY<T, 5>(w, tanhalf(0.5f * th[T * NQ + 11], G));
    ringB<T>(w, lane);
}

// layer entering in layout B (theta row T; ends in layout A)
template<int T>
__device__ __forceinline__ void layerB(v2f* w, const float* __restrict__ th,
                                       int lane, float& G, float* sh) {
    regRY<T, 0>(w, tanhalf(0.5f * th[T * NQ + 6],  G));
    regRY<T, 1>(w, tanhalf(0.5f * th[T * NQ + 7],  G));
    regRY<T, 2>(w, tanhalf(0.5f * th[T * NQ + 8],  G));
    regRY<T, 3>(w, tanhalf(0.5f * th[T * NQ + 9],  G));
    regRY<T, 4>(w, tanhalf(0.5f * th[T * NQ + 10], G));
    regRY<T, 5>(w, tanhalf(0.5f * th[T * NQ + 11], G));
    transpose64(w, sh, lane);
    regRY<T, 0>(w, tanhalf(0.5f * th[T * NQ + 0], G));
    regRY<T, 1>(w, tanhalf(0.5f * th[T * NQ + 1], G));
    regRY<T, 2>(w, tanhalf(0.5f * th[T * NQ + 2], G));
    regRY<T, 3>(w, tanhalf(0.5f * th[T * NQ + 3], G));
    regRY<T, 4>(w, tanhalf(0.5f * th[T * NQ + 4], G));
    regRY<T, 5>(w, tanhalf(0.5f * th[T * NQ + 5], G));
    ringA<T>(w, lane);
}

__global__ __launch_bounds__(128)
void qc_kernel(const float* __restrict__ x, const float* __restrict__ theta,
               float* __restrict__ out) {
    __shared__ float shbuf[2][32 * 68];
    const int lane = threadIdx.x & 63;
    const int wid  = threadIdx.x >> 6;
    const int b = __builtin_amdgcn_readfirstlane((blockIdx.x << 1) + wid);
    float* sh = &shbuf[wid][0];

    alignas(16) v2f w[32];

    // ---- init in layout A, layer-0 thetas folded: RY(th)RY(x)|0> = RY(x+th)|0>
    float L = 1.0f;
    #pragma unroll
    for (int q = 6; q < NQ; ++q) {
        float s, c;
        __sincosf(0.5f * (x[b * NQ + q] + theta[q]), &s, &c);
        L *= ((lane >> (q - 6)) & 1) ? s : c;
    }
    VAT(w, 0) = L;
    #pragma unroll
    for (int q = 0; q < 6; ++q) {
        float s, c;
        __sincosf(0.5f * (x[b * NQ + q] + theta[q]), &s, &c);
        #pragma unroll
        for (int r = 0; r < (1 << q); ++r) {
            float vr = VAT(w, r);
            VAT(w, r + (1 << q)) = vr * s;
            VAT(w, r)            = vr * c;
        }
    }

    float G = 1.0f;            // product of cosines over layers 1..3
    ringA<0>(w, lane);         // layer-0 ring (gates folded into init)
    layerA<1>(w, theta, lane, G, sh);   // A -> B
    layerB<2>(w, theta, lane, G, sh);   // B -> A
    layerA<3>(w, theta, lane, G, sh);   // A -> B
    // final: layout B, renaming powers (4,4)

    // ---- epilogue: out[b,q] = G^2 * sum_d v^2 * (1-2 bit_q(d))
    #pragma unroll
    for (int k = 0; k < 32; ++k) w[k] = w[k] * w[k];

    float Dq[6];
    float s1[32];
    {
        float d = 0.f;
        #pragma unroll
        for (int k = 0; k < 32; ++k) {
            const int i0 = (2 * k)     ^ (((2 * k)     & 3) << 4);
            const int i1 = (2 * k + 1) ^ (((2 * k + 1) & 3) << 4);
            s1[k] = VAT(w, i0) + VAT(w, i1);
            d    += VAT(w, i0) - VAT(w, i1);
        }
        Dq[0] = d;
    }
    #pragma unroll
    for (int j = 1; j < 6; ++j) {
        const int n = 32 >> j;
        float d = 0.f;
        #pragma unroll
        for (int k = 0; k < n; ++k) {
            d    += s1[2 * k] - s1[2 * k + 1];
            s1[k] = s1[2 * k] + s1[2 * k + 1];
        }
        Dq[j] = d;
    }
    const float tot = s1[0];

    float res[NQ];
    res[0] = wave_red<rowmask6(0, 4)>(tot);   // lane qubits 0..5
    res[1] = wave_red<rowmask6(1, 4)>(tot);
    res[2] = wave_red<rowmask6(2, 4)>(tot);
    res[3] = wave_red<rowmask6(3, 4)>(tot);
    res[4] = wave_red<rowmask6(4, 4)>(tot);
    res[5] = wave_red<rowmask6(5, 4)>(tot);
    #pragma unroll
    for (int j = 0; j < 6; ++j) res[6 + j] = wave_red<0>(Dq[j]);  // reg qubits

    float myres = res[0];
    #pragma unroll
    for (int q = 1; q < NQ; ++q) myres = (lane == q) ? res[q] : myres;
    myres *= G * G;
    if (lane < NQ) out[b * NQ + lane] = myres;
}

extern "C" void kernel_launch(void* const* d_in, const int* in_sizes, int n_in,
                              void* d_out, int out_size, void* d_ws, size_t ws_size,
                              hipStream_t stream) {
    const float* x     = (const float*)d_in[0];
    const float* theta = (const float*)d_in[1];
    float* out = (float*)d_out;
    dim3 grid(BATCH / 2), block(128);
    qc_kernel<<<grid, block, 0, stream>>>(x, theta, out);
}